// Round 8
// baseline (847.950 us; speedup 1.0000x reference)
//
#include <hip/hip_runtime.h>
#include <hip/hip_fp16.h>

typedef _Float16 f16;
typedef _Float16 f16x4 __attribute__((ext_vector_type(4)));
typedef _Float16 f16x8 __attribute__((ext_vector_type(8)));
typedef float    f32x4 __attribute__((ext_vector_type(4)));

#define NEG_INF (-__builtin_inff())
#define AS1 __attribute__((address_space(1)))
#define AS3 __attribute__((address_space(3)))
#define GLOAD_LDS16(g, l) \
    __builtin_amdgcn_global_load_lds((AS1 const void*)(g), (AS3 void*)(l), 16, 0, 0)
// v_exp_f32 computes 2^x; this builtin maps to it directly (NOT __exp2f, which
// collides with glibc math.h and does not exist as a HIP device function).
#define EXP2F(x) __builtin_amdgcn_exp2f(x)
// s_barrier is IntrNoMem at IR level: bracket with compile-time fences so no
// memory op (ds_read / global_load_lds) can be scheduled across a phase edge.
#define BARRIER() do { asm volatile("" ::: "memory"); \
                       __builtin_amdgcn_s_barrier(); \
                       asm volatile("" ::: "memory"); } while (0)

// ---------------------------------------------------------------- converts
__global__ __launch_bounds__(256) void cvt_f32_f16(const float* __restrict__ in,
                                                   f16* __restrict__ out, int n4) {
    int i = blockIdx.x * 256 + threadIdx.x;
    if (i >= n4) return;
    float4 v = ((const float4*)in)[i];
    f16x4 h = {(f16)v.x, (f16)v.y, (f16)v.z, (f16)v.w};
    ((f16x4*)out)[i] = h;
}

// ---------------------------------------------------------------- GEMM C = A * Bt^T
// r3 skeleton (barriers + staging ledger UNCHANGED, measured race-free) +
// fragment-read software pipelining under the MFMA clusters.
// r7 BUG (absmax 1.22): ph3 prefetched bf0(t+1) BEFORE the ph3 MFMA consumed
// bf0(t) -- register clobber, wrong operand. Fix: afA(t+1) prefetch rides the
// ph3 MFMA cluster (8/12 reads); bf0(t+1) prefetch issues AFTER the cluster
// (4 reads; latency hides under ph3-end barrier + t+1 ph0 STG + barrier, and
// t+1 ph0's lgkmcnt(0) guarantees completion before use).
//   ph0 MFMA(afA,bf0)  | prefetch bf1(t)
//   ph1 MFMA(afA,bf1)  | prefetch afB(t,m1)
//   ph2 MFMA(afB,bf1)  |
//   ph3 vmcnt+BAR; MFMA(afB,bf0) | prefetch afA(t+1); then prefetch bf0(t+1)
// Ledger entering tile t: in-flight = B(t+1) 4; t issues A(t+1)@ph0/1,
// B(t+2)@ph2/3; ph3 vmcnt(4) retires B(t+1)+A(t+1). t+2>=NT: vmcnt(0).
template <typename CT>
__global__ __launch_bounds__(512) void gemm256(const f16* __restrict__ A,
                                               const f16* __restrict__ Bt,
                                               CT* __restrict__ C,
                                               int M, int N, int K) {
    __shared__ __align__(16) f16 smem[65536];     // LA[2][2][8192] | LB[2][2][8192]
    f16* LA = smem;
    f16* LB = smem + 32768;

    const int tid  = threadIdx.x;
    const int wave = tid >> 6, lane = tid & 63;
    const int quad = lane >> 4, m16 = lane & 15;
    const int wm = wave >> 2, wn = wave & 3;

    // bijective XCD-aware block swizzle (m204 form)
    const int ntn = N >> 8;
    const int nwg = (M >> 8) * ntn;
    const int q8 = nwg >> 3, r8 = nwg & 7;
    const int xcd = blockIdx.x & 7, idx = blockIdx.x >> 3;
    const int swz = (xcd < r8 ? xcd * (q8 + 1) : r8 * (q8 + 1) + (xcd - r8) * q8) + idx;
    const int bm = (swz / ntn) << 8;
    const int bn = (swz % ntn) << 8;

    // staging: thread tid fills linear LDS elems tid*8 (+4096 for rows 64..127);
    // source column-granule XOR-pre-permuted so swizzled reads see logical data.
    const int rowW = tid >> 3;                         // 0..63
    const int gsrc = (tid & 7) ^ (rowW & 7);
    const f16* gA0 = A  + (size_t)(bm + rowW) * K + gsrc * 8;
    const f16* gA1 = A  + (size_t)(bm + 128 + rowW) * K + gsrc * 8;
    const f16* gB0 = Bt + (size_t)(bn + rowW) * K + gsrc * 8;
    const f16* gB1 = Bt + (size_t)(bn + 128 + rowW) * K + gsrc * 8;
    const size_t rstep = (size_t)64 * K;
    const int lw = wave * 512;                         // wave-uniform LDS elem offset

#define STG(dstbase, gp, kt) do { \
    GLOAAD_LDS16_GUARD \
    GLOAD_LDS16((gp) + (size_t)(kt) * 64,         (dstbase) + lw); \
    GLOAD_LDS16((gp) + (size_t)(kt) * 64 + rstep, (dstbase) + lw + 4096); } while (0)
#define GLOAAD_LDS16_GUARD

    // fragment LDS offsets (elems): row*64 + (((ks*4+quad) ^ (row&7))*8
    int foff[2];
#pragma unroll
    for (int ks = 0; ks < 2; ++ks)
        foff[ks] = (((ks << 2) | quad) ^ (m16 & 7)) * 8;
    const int arow = wm * 8192 + m16 * 64;             // + mt*1024
    const int brow = (wn >> 1) * 8192 + (wn & 1) * 4096 + m16 * 64;   // + nt*1024

    f32x4 acc[8][4];
#pragma unroll
    for (int i = 0; i < 8; ++i)
#pragma unroll
        for (int j = 0; j < 4; ++j)
#pragma unroll
            for (int e = 0; e < 4; ++e) acc[i][j][e] = 0.f;

    const int NT = K >> 6;

    // prologue: tile0 {A0,A1,B0,B1} + tile1 {B0,B1}; vmcnt(4) lands tile0;
    // then prefetch tile0's ph0 fragments (afA m0 + bf0) before entering loop.
    STG(LA, gA0, 0); STG(LA + 8192, gA1, 0);
    STG(LB, gB0, 0); STG(LB + 8192, gB1, 0);
    STG(LB + 16384, gB0, 1); STG(LB + 16384 + 8192, gB1, 1);
    asm volatile("s_waitcnt vmcnt(4)" ::: "memory");
    BARRIER();

    f16x8 afA[4][2], afB[4][2], bf0[2][2], bf1[2][2];
#pragma unroll
    for (int mt = 0; mt < 4; ++mt)
#pragma unroll
        for (int ks = 0; ks < 2; ++ks)
            afA[mt][ks] = *(const f16x8*)(LA + arow + mt * 1024 + foff[ks]);
#pragma unroll
    for (int nt = 0; nt < 2; ++nt)
#pragma unroll
        for (int ks = 0; ks < 2; ++ks)
            bf0[nt][ks] = *(const f16x8*)(LB + brow + nt * 1024 + foff[ks]);

    for (int t = 0; t < NT; ++t) {
        const int bo = (t & 1) * 16384;
        const f16* pa = LA + bo + arow;
        const f16* pb = LB + bo + brow;
        const f16* pa1 = LA + (bo ^ 16384) + arow;     // next tile's buffer
        const f16* pb1 = LB + (bo ^ 16384) + brow;

        // ---- phase 0: stage A-h0(t+1); MFMA(afA,bf0) ∥ prefetch bf1(t)
        if (t + 1 < NT) STG(LA + (bo ^ 16384), gA0, t + 1);
        BARRIER();
        asm volatile("s_waitcnt lgkmcnt(0)" ::: "memory");
        __builtin_amdgcn_s_setprio(1);
#pragma unroll
        for (int nt = 0; nt < 2; ++nt)
#pragma unroll
            for (int ks = 0; ks < 2; ++ks)
                bf1[nt][ks] = *(const f16x8*)(pb + (nt + 2) * 1024 + foff[ks]);
#pragma unroll
        for (int mt = 0; mt < 4; ++mt)
#pragma unroll
            for (int nt = 0; nt < 2; ++nt)
#pragma unroll
                for (int ks = 0; ks < 2; ++ks)
                    acc[mt][nt] = __builtin_amdgcn_mfma_f32_16x16x32_f16(
                        afA[mt][ks], bf0[nt][ks], acc[mt][nt], 0, 0, 0);
        __builtin_amdgcn_s_setprio(0);
        BARRIER();

        // ---- phase 1: stage A-h1(t+1); MFMA(afA,bf1) ∥ prefetch afB(t,m1)
        if (t + 1 < NT) STG(LA + (bo ^ 16384) + 8192, gA1, t + 1);
        BARRIER();
        asm volatile("s_waitcnt lgkmcnt(0)" ::: "memory");
        __builtin_amdgcn_s_setprio(1);
#pragma unroll
        for (int mt = 0; mt < 4; ++mt)
#pragma unroll
            for (int ks = 0; ks < 2; ++ks)
                afB[mt][ks] = *(const f16x8*)(pa + (mt + 4) * 1024 + foff[ks]);
#pragma unroll
        for (int mt = 0; mt < 4; ++mt)
#pragma unroll
            for (int nt = 0; nt < 2; ++nt)
#pragma unroll
                for (int ks = 0; ks < 2; ++ks)
                    acc[mt][nt + 2] = __builtin_amdgcn_mfma_f32_16x16x32_f16(
                        afA[mt][ks], bf1[nt][ks], acc[mt][nt + 2], 0, 0, 0);
        __builtin_amdgcn_s_setprio(0);
        BARRIER();

        // ---- phase 2: stage B-h0(t+2); MFMA(afB,bf1)
        if (t + 2 < NT) STG(LB + bo, gB0, t + 2);
        BARRIER();
        asm volatile("s_waitcnt lgkmcnt(0)" ::: "memory");
        __builtin_amdgcn_s_setprio(1);
#pragma unroll
        for (int mt = 0; mt < 4; ++mt)
#pragma unroll
            for (int nt = 0; nt < 2; ++nt)
#pragma unroll
                for (int ks = 0; ks < 2; ++ks)
                    acc[mt + 4][nt + 2] = __builtin_amdgcn_mfma_f32_16x16x32_f16(
                        afB[mt][ks], bf1[nt][ks], acc[mt + 4][nt + 2], 0, 0, 0);
        __builtin_amdgcn_s_setprio(0);
        BARRIER();

        // ---- phase 3: stage B-h1(t+2); vmcnt+BAR (A/B(t+1) visible);
        //      MFMA(afB,bf0) ∥ prefetch afA(t+1); THEN prefetch bf0(t+1)
        //      (bf0(t) must be consumed by the MFMA before being overwritten)
        if (t + 2 < NT) STG(LB + bo + 8192, gB1, t + 2);
        if (t + 2 < NT) { asm volatile("s_waitcnt vmcnt(4)" ::: "memory"); }
        else            { asm volatile("s_waitcnt vmcnt(0)" ::: "memory"); }
        BARRIER();
        __builtin_amdgcn_s_setprio(1);
        if (t + 1 < NT) {
#pragma unroll
            for (int mt = 0; mt < 4; ++mt)
#pragma unroll
                for (int ks = 0; ks < 2; ++ks)
                    afA[mt][ks] = *(const f16x8*)(pa1 + mt * 1024 + foff[ks]);
        }
#pragma unroll
        for (int mt = 0; mt < 4; ++mt)
#pragma unroll
            for (int nt = 0; nt < 2; ++nt)
#pragma unroll
                for (int ks = 0; ks < 2; ++ks)
                    acc[mt + 4][nt] = __builtin_amdgcn_mfma_f32_16x16x32_f16(
                        afB[mt][ks], bf0[nt][ks], acc[mt + 4][nt], 0, 0, 0);
        if (t + 1 < NT) {
#pragma unroll
            for (int nt = 0; nt < 2; ++nt)
#pragma unroll
                for (int ks = 0; ks < 2; ++ks)
                    bf0[nt][ks] = *(const f16x8*)(pb1 + nt * 1024 + foff[ks]);
        }
        __builtin_amdgcn_s_setprio(0);
        BARRIER();
    }
#undef STG

    // epilogue: row = bm + wm*128 + mt*16 + quad*4 + r, col = bn + wn*64 + nt*16 + m16
#pragma unroll
    for (int mt = 0; mt < 8; ++mt)
#pragma unroll
        for (int r = 0; r < 4; ++r) {
            int row = bm + wm * 128 + mt * 16 + quad * 4 + r;
            CT* cp = C + (size_t)row * N + bn + wn * 64 + m16;
#pragma unroll
            for (int nt = 0; nt < 4; ++nt) cp[nt * 16] = (CT)acc[mt][nt][r];
        }
}

// ---------------------------------------------------------------- RoPE (q,k only)
// Paged cache scatter+gather through an injective block_table is the identity on
// (b,s) -> skip the cache. qkv row: q 0:4096 | k 4096:5120 | v 5120:6144.
__global__ __launch_bounds__(256) void rope_qk(const f16* __restrict__ qkv,
                                               const float* __restrict__ freqs,
                                               f16* __restrict__ qh,
                                               f16* __restrict__ kk) {
    int idx  = blockIdx.x * 256 + threadIdx.x;     // B*S*40heads*64pairs
    int row  = idx / 2560;
    int p    = idx - row * 2560;
    int b    = row >> 11, s = row & 2047;
    int head = p >> 6, i = p & 63;
    const f16* src = qkv + (size_t)row * 6144 + head * 128 + 2 * i;
    float v0 = (float)src[0], v1 = (float)src[1];
    float c  = freqs[s * 128 + 2 * i];
    float sn = freqs[s * 128 + 2 * i + 1];
    float r0 = v0 * c - v1 * sn;
    float r1 = v1 * c + v0 * sn;
    f16* dst = (head < 32)
        ? qh + (((size_t)(b * 32 + head)) * 2048 + s) * 128 + 2 * i
        : kk + (((size_t)(b * 8 + head - 32)) * 2048 + s) * 128 + 2 * i;
    dst[0] = (f16)r0; dst[1] = (f16)r1;
}

// ---------------------------------------------------------------- V transpose (LDS-tiled)
__global__ __launch_bounds__(256) void transpose_v(const f16* __restrict__ qkv,
                                                   f16* __restrict__ vvt) {
    __shared__ f16 T[64][72];
    const int st = blockIdx.x, dt = blockIdx.y;
    const int b = blockIdx.z >> 3, kvh = blockIdx.z & 7;
    const int tid = threadIdx.x;
    const int sr = tid >> 3, c8 = (tid & 7) * 8;
#pragma unroll
    for (int rep = 0; rep < 2; ++rep) {
        int sl = rep * 32 + sr;
        *(f16x8*)&T[sl][c8] =
            *(const f16x8*)(qkv + (size_t)(b * 2048 + st * 64 + sl) * 6144
                            + 5120 + kvh * 128 + dt * 64 + c8);
    }
    __syncthreads();
#pragma unroll
    for (int rep = 0; rep < 2; ++rep) {
        int dl = rep * 32 + sr;
        f16x8 v;
#pragma unroll
        for (int j = 0; j < 8; ++j) v[j] = T[c8 + j][dl];
        *(f16x8*)(vvt + (((size_t)(b * 8 + kvh)) * 128 + dt * 64 + dl) * 2048
                  + st * 64 + c8) = v;
    }
}

// ---------------------------------------------------------------- flash attention v5
// v4 body + T14 async staging: K/V tile held in regs (+32 VGPR), ds_written at
// tile top; NEXT tile's global loads issued immediately after, then only
// lgkmcnt(0) + raw s_barrier (NOT __syncthreads, whose vmcnt(0) drain would
// expose the load latency) -- loads ride under QK^T+softmax+PV (~5 kcy).
// Also: log2-domain softmax (v_exp_f32 is natively 2^x; saves the x*log2e
// multiply inside __expf) and EXACT defer-rescale (skip alpha/oacc rescale
// when the wave-uniform tile max doesn't grow; skipped factor is exp2(0)=1).
__global__ __launch_bounds__(256) void attn_fused(const f16* __restrict__ qh,
                                                  const f16* __restrict__ kk,
                                                  const f16* __restrict__ vvt,
                                                  const int* __restrict__ seqlens,
                                                  f16* __restrict__ out) {
    __shared__ f16 KsPs[64 * 136];   // Ks: [key][d] stride 136; Ps overlays offset 0
    __shared__ f16 Vs[128][72];      // [d][key], stride 72 (2-way free)
    const int pair = blockIdx.x;     // 0..15
    const int h = blockIdx.y, b = blockIdx.z;
    const int kvh = h >> 2;
    const int tid = threadIdx.x, wave = tid >> 6, lane = tid & 63;
    const int quad = lane >> 4, m16 = lane & 15;
    f16* Ps = KsPs;

    const int seqlen = seqlens[b];
    const f16* kbp = kk  + ((size_t)(b * 8 + kvh) * 2048) * 128;
    const f16* vbp = vvt + ((size_t)(b * 8 + kvh) * 128) * 2048;

    // scale * log2(e): softmax runs in the log2 domain
    const float SCL2 = 0.08838834764831845f * 1.4426950408889634f;

    for (int half = 0; half < 2; ++half) {
        const int qt = half ? pair : (31 - pair);   // heavy tile first
        const int qbase = qt * 64;
        const int qw = qbase + wave * 16;

        const f16* qptr = qh + (((size_t)(b * 32 + h)) * 2048 + qw + m16) * 128;
        f16x8 qf[4];
#pragma unroll
        for (int c = 0; c < 4; ++c) qf[c] = *(const f16x8*)(qptr + c * 32 + quad * 8);

        float m_i[4], l_i[4];
        f32x4 oacc[8];
#pragma unroll
        for (int r = 0; r < 4; ++r) { m_i[r] = NEG_INF; l_i[r] = 0.f; }
#pragma unroll
        for (int dt = 0; dt < 8; ++dt)
#pragma unroll
            for (int e = 0; e < 4; ++e) oacc[dt][e] = 0.f;

        int kmax = qbase + 64; if (seqlen < kmax) kmax = seqlen;

        // prefetch tile 0 into registers
        f16x8 gk[4], gv[4];
#pragma unroll
        for (int it = 0; it < 4; ++it) {
            int g = it * 256 + tid;
            gk[it] = *(const f16x8*)(kbp + (size_t)(g >> 4) * 128 + (g & 15) * 8);
            gv[it] = *(const f16x8*)(vbp + (size_t)(g >> 3) * 2048 + (g & 7) * 8);
        }

        for (int kt = 0; kt < kmax; kt += 64) {
            BARRIER();   // all waves' Ks/Ps/Vs reads of prev iter are complete
            // reg -> LDS (K tile: 64 keys x 128 d; V^T tile: 128 d x 64 keys)
#pragma unroll
            for (int it = 0; it < 4; ++it) {
                int g = it * 256 + tid;
                *(f16x8*)&KsPs[(g >> 4) * 136 + (g & 15) * 8] = gk[it];
                *(f16x8*)&Vs[g >> 3][(g & 7) * 8] = gv[it];
            }
            // issue next tile's loads; they stay in flight across the barrier
            if (kt + 64 < kmax) {
#pragma unroll
                for (int it = 0; it < 4; ++it) {
                    int g = it * 256 + tid;
                    gk[it] = *(const f16x8*)(kbp + (size_t)(kt + 64 + (g >> 4)) * 128 + (g & 15) * 8);
                    gv[it] = *(const f16x8*)(vbp + (size_t)(g >> 3) * 2048 + (kt + 64) + (g & 7) * 8);
                }
            }
            asm volatile("s_waitcnt lgkmcnt(0)" ::: "memory");  // LDS writes visible
            BARRIER();                                          // vmcnt NOT drained

            // S = Q K^T
            f32x4 sc[4];
#pragma unroll
            for (int nt = 0; nt < 4; ++nt) {
                f32x4 s = {0.f, 0.f, 0.f, 0.f};
#pragma unroll
                for (int c = 0; c < 4; ++c) {
                    f16x8 kf = *(const f16x8*)&KsPs[(nt * 16 + m16) * 136 + c * 32 + quad * 8];
                    s = __builtin_amdgcn_mfma_f32_16x16x32_f16(qf[c], kf, s, 0, 0, 0);
                }
                sc[nt] = s;
            }

            // scale + mask (log2 domain) + online softmax
            float sv[4][4];
            float mt[4] = {NEG_INF, NEG_INF, NEG_INF, NEG_INF};
#pragma unroll
            for (int nt = 0; nt < 4; ++nt) {
                int kpos = kt + nt * 16 + m16;
#pragma unroll
                for (int r = 0; r < 4; ++r) {
                    int qpos = qw + quad * 4 + r;
                    float sx = sc[nt][r] * SCL2;
                    sx = (kpos <= qpos && kpos < seqlen) ? sx : NEG_INF;
                    sv[nt][r] = sx;
                    mt[r] = fmaxf(mt[r], sx);
                }
            }
#pragma unroll
            for (int off = 1; off < 16; off <<= 1)
#pragma unroll
                for (int r = 0; r < 4; ++r)
                    mt[r] = fmaxf(mt[r], __shfl_xor(mt[r], off, 64));

            // exact defer: mt/m_i are wave-uniform -> uniform branch; skip the
            // alpha+rescale pass entirely when no row's max grew (alpha==1).
            float mm[4];
            bool grow = (mt[0] > m_i[0]) | (mt[1] > m_i[1]) |
                        (mt[2] > m_i[2]) | (mt[3] > m_i[3]);
            if (grow) {
#pragma unroll
                for (int r = 0; r < 4; ++r) {
                    float mo = m_i[r];
                    float mn = fmaxf(mo, mt[r]);
                    float mmr = fmaxf(mn, -1e30f);
                    float a = EXP2F(mo - mmr);
                    m_i[r] = mn;
                    mm[r] = mmr;
                    l_i[r] *= a;
#pragma unroll
                    for (int dt = 0; dt < 8; ++dt) oacc[dt][r] *= a;
                }
            } else {
#pragma unroll
                for (int r = 0; r < 4; ++r) mm[r] = fmaxf(m_i[r], -1e30f);
            }
            float rs[4] = {0.f, 0.f, 0.f, 0.f};
#pragma unroll
            for (int nt = 0; nt < 4; ++nt)
#pragma unroll
                for (int r = 0; r < 4; ++r) {
                    float pv = EXP2F(sv[nt][r] - mm[r]);
                    sv[nt][r] = pv;
                    rs[r] += pv;
                }
#pragma unroll
            for (int off = 1; off < 16; off <<= 1)
#pragma unroll
                for (int r = 0; r < 4; ++r) rs[r] += __shfl_xor(rs[r], off, 64);
#pragma unroll
            for (int r = 0; r < 4; ++r) l_i[r] += rs[r];

            BARRIER();   // ALL waves done reading Ks before Ps overwrites

            // P: C-layout regs -> wave-private LDS region -> A-layout fragments
#pragma unroll
            for (int nt = 0; nt < 4; ++nt)
#pragma unroll
                for (int r = 0; r < 4; ++r)
                    Ps[(wave * 16 + quad * 4 + r) * 72 + nt * 16 + m16] = (f16)sv[nt][r];

            f16x8 pf[2];
#pragma unroll
            for (int c = 0; c < 2; ++c)
                pf[c] = *(const f16x8*)&Ps[(wave * 16 + m16) * 72 + c * 32 + quad * 8];
#pragma unroll
            for (int dt = 0; dt < 8; ++dt)
#pragma unroll
                for (int c = 0; c < 2; ++c) {
                    f16x8 vf = *(const f16x8*)&Vs[dt * 16 + m16][c * 32 + quad * 8];
                    oacc[dt] = __builtin_amdgcn_mfma_f32_16x16x32_f16(pf[c], vf, oacc[dt], 0, 0, 0);
                }
        }

        // normalize + write [B,S,NH*HD]
#pragma unroll
        for (int r = 0; r < 4; ++r) {
            int qpos = qw + quad * 4 + r;
            float inv = 1.0f / l_i[r];
            f16* op = out + ((size_t)b * 2048 + qpos) * 4096 + h * 128;
#pragma unroll
            for (int dt = 0; dt < 8; ++dt)
                op[dt * 16 + m16] = (f16)(oacc[dt][r] * inv);
        }
        // next half's k-loop starts with BARRIER(), protecting LDS reuse
    }
}

// ---------------------------------------------------------------- launch
extern "C" void kernel_launch(void* const* d_in, const int* in_sizes, int n_in,
                              void* d_out, int out_size, void* d_ws, size_t ws_size,
                              hipStream_t stream) {
    const float* x     = (const float*)d_in[0];   // [2,2048,4096]
    const float* wqkv  = (const float*)d_in[1];   // [6144,4096]
    const float* wo    = (const float*)d_in[2];   // [4096,4096]
    const float* freqs = (const float*)d_in[3];   // [2048,1,64,2]
    const int*   seql  = (const int*)d_in[7];     // [2]
    float* out = (float*)d_out;

    char* ws = (char*)d_ws;
    size_t o = 0;
    f16* xh    = (f16*)(ws + o); o += (size_t)4096 * 4096 * 2;   // reused as attn_h
    f16* wqkvh = (f16*)(ws + o); o += (size_t)6144 * 4096 * 2;
    f16* woh   = (f16*)(ws + o); o += (size_t)4096 * 4096 * 2;
    f16* qkvh  = (f16*)(ws + o); o += (size_t)4096 * 6144 * 2;
    f16* qhp   = (f16*)(ws + o); o += (size_t)4096 * 4096 * 2;
    f16* kkp   = (f16*)(ws + o); o += (size_t)4096 * 8 * 128 * 2;
    f16* vvt   = (f16*)(ws + o); o += (size_t)4096 * 8 * 128 * 2;
    f16* attnh = xh;  // xh dead after GEMM1

    cvt_f32_f16<<<16384, 256, 0, stream>>>(x, xh, 4194304);
    cvt_f32_f16<<<24576, 256, 0, stream>>>(wqkv, wqkvh, 6291456);
    cvt_f32_f16<<<16384, 256, 0, stream>>>(wo, woh, 4194304);

    gemm256<f16><<<384, 512, 0, stream>>>(xh, wqkvh, qkvh, 4096, 6144, 4096);

    rope_qk<<<40960, 256, 0, stream>>>(qkvh, freqs, qhp, kkp);
    transpose_v<<<dim3(32, 2, 16), 256, 0, stream>>>(qkvh, vvt);

    attn_fused<<<dim3(16, 32, 2), 256, 0, stream>>>(qhp, kkp, vvt, seql, attnh);

    gemm256<float><<<256, 512, 0, stream>>>(attnh, woh, out, 4096, 4096, 4096);
}

// Round 9
// 830.201 us; speedup vs baseline: 1.0214x; 1.0214x over previous
//
#include <hip/hip_runtime.h>
#include <hip/hip_fp16.h>

typedef _Float16 f16;
typedef _Float16 f16x4 __attribute__((ext_vector_type(4)));
typedef _Float16 f16x8 __attribute__((ext_vector_type(8)));
typedef float    f32x4 __attribute__((ext_vector_type(4)));

#define NEG_INF (-__builtin_inff())
#define AS1 __attribute__((address_space(1)))
#define AS3 __attribute__((address_space(3)))
#define GLOAD_LDS16(g, l) \
    __builtin_amdgcn_global_load_lds((AS1 const void*)(g), (AS3 void*)(l), 16, 0, 0)
// v_exp_f32 computes 2^x; this builtin maps to it directly (NOT __exp2f, which
// collides with glibc math.h and does not exist as a HIP device function).
#define EXP2F(x) __builtin_amdgcn_exp2f(x)
// s_barrier is IntrNoMem at IR level: bracket with compile-time fences so no
// memory op (ds_read / global_load_lds) can be scheduled across a phase edge.
#define BARRIER() do { asm volatile("" ::: "memory"); \
                       __builtin_amdgcn_s_barrier(); \
                       asm volatile("" ::: "memory"); } while (0)

// ---------------------------------------------------------------- converts
__global__ __launch_bounds__(256) void cvt_f32_f16(const float* __restrict__ in,
                                                   f16* __restrict__ out, int n4) {
    int i = blockIdx.x * 256 + threadIdx.x;
    if (i >= n4) return;
    float4 v = ((const float4*)in)[i];
    f16x4 h = {(f16)v.x, (f16)v.y, (f16)v.z, (f16)v.w};
    ((f16x4*)out)[i] = h;
}

// ---------------------------------------------------------------- GEMM C = A * Bt^T
// FROZEN (r8, measured 258 us, MfmaUtil ~34): r3 barrier/staging ledger +
// fragment prefetch under MFMA clusters. Three scheduling attempts (r4 deeper
// vmcnt, r6/r8 read pipelining) were null or negative: with 8 waves / 4 SIMDs
// the cross-wave overlap already hides LDS reads; ~34% is this structure's
// ceiling. Do not touch.
template <typename CT>
__global__ __launch_bounds__(512) void gemm256(const f16* __restrict__ A,
                                               const f16* __restrict__ Bt,
                                               CT* __restrict__ C,
                                               int M, int N, int K) {
    __shared__ __align__(16) f16 smem[65536];     // LA[2][2][8192] | LB[2][2][8192]
    f16* LA = smem;
    f16* LB = smem + 32768;

    const int tid  = threadIdx.x;
    const int wave = tid >> 6, lane = tid & 63;
    const int quad = lane >> 4, m16 = lane & 15;
    const int wm = wave >> 2, wn = wave & 3;

    // bijective XCD-aware block swizzle (m204 form)
    const int ntn = N >> 8;
    const int nwg = (M >> 8) * ntn;
    const int q8 = nwg >> 3, r8 = nwg & 7;
    const int xcd = blockIdx.x & 7, idx = blockIdx.x >> 3;
    const int swz = (xcd < r8 ? xcd * (q8 + 1) : r8 * (q8 + 1) + (xcd - r8) * q8) + idx;
    const int bm = (swz / ntn) << 8;
    const int bn = (swz % ntn) << 8;

    // staging: thread tid fills linear LDS elems tid*8 (+4096 for rows 64..127);
    // source column-granule XOR-pre-permuted so swizzled reads see logical data.
    const int rowW = tid >> 3;                         // 0..63
    const int gsrc = (tid & 7) ^ (rowW & 7);
    const f16* gA0 = A  + (size_t)(bm + rowW) * K + gsrc * 8;
    const f16* gA1 = A  + (size_t)(bm + 128 + rowW) * K + gsrc * 8;
    const f16* gB0 = Bt + (size_t)(bn + rowW) * K + gsrc * 8;
    const f16* gB1 = Bt + (size_t)(bn + 128 + rowW) * K + gsrc * 8;
    const size_t rstep = (size_t)64 * K;
    const int lw = wave * 512;                         // wave-uniform LDS elem offset

#define STG(dstbase, gp, kt) do { \
    GLOAD_LDS16((gp) + (size_t)(kt) * 64,         (dstbase) + lw); \
    GLOAD_LDS16((gp) + (size_t)(kt) * 64 + rstep, (dstbase) + lw + 4096); } while (0)

    // fragment LDS offsets (elems): row*64 + (((ks*4+quad) ^ (row&7))*8
    int foff[2];
#pragma unroll
    for (int ks = 0; ks < 2; ++ks)
        foff[ks] = (((ks << 2) | quad) ^ (m16 & 7)) * 8;
    const int arow = wm * 8192 + m16 * 64;             // + mt*1024
    const int brow = (wn >> 1) * 8192 + (wn & 1) * 4096 + m16 * 64;   // + nt*1024

    f32x4 acc[8][4];
#pragma unroll
    for (int i = 0; i < 8; ++i)
#pragma unroll
        for (int j = 0; j < 4; ++j)
#pragma unroll
            for (int e = 0; e < 4; ++e) acc[i][j][e] = 0.f;

    const int NT = K >> 6;

    // prologue: tile0 {A0,A1,B0,B1} + tile1 {B0,B1}; vmcnt(4) lands tile0;
    // then prefetch tile0's ph0 fragments (afA m0 + bf0) before entering loop.
    STG(LA, gA0, 0); STG(LA + 8192, gA1, 0);
    STG(LB, gB0, 0); STG(LB + 8192, gB1, 0);
    STG(LB + 16384, gB0, 1); STG(LB + 16384 + 8192, gB1, 1);
    asm volatile("s_waitcnt vmcnt(4)" ::: "memory");
    BARRIER();

    f16x8 afA[4][2], afB[4][2], bf0[2][2], bf1[2][2];
#pragma unroll
    for (int mt = 0; mt < 4; ++mt)
#pragma unroll
        for (int ks = 0; ks < 2; ++ks)
            afA[mt][ks] = *(const f16x8*)(LA + arow + mt * 1024 + foff[ks]);
#pragma unroll
    for (int nt = 0; nt < 2; ++nt)
#pragma unroll
        for (int ks = 0; ks < 2; ++ks)
            bf0[nt][ks] = *(const f16x8*)(LB + brow + nt * 1024 + foff[ks]);

    for (int t = 0; t < NT; ++t) {
        const int bo = (t & 1) * 16384;
        const f16* pa = LA + bo + arow;
        const f16* pb = LB + bo + brow;
        const f16* pa1 = LA + (bo ^ 16384) + arow;     // next tile's buffer
        const f16* pb1 = LB + (bo ^ 16384) + brow;

        // ---- phase 0: stage A-h0(t+1); MFMA(afA,bf0) ∥ prefetch bf1(t)
        if (t + 1 < NT) STG(LA + (bo ^ 16384), gA0, t + 1);
        BARRIER();
        asm volatile("s_waitcnt lgkmcnt(0)" ::: "memory");
        __builtin_amdgcn_s_setprio(1);
#pragma unroll
        for (int nt = 0; nt < 2; ++nt)
#pragma unroll
            for (int ks = 0; ks < 2; ++ks)
                bf1[nt][ks] = *(const f16x8*)(pb + (nt + 2) * 1024 + foff[ks]);
#pragma unroll
        for (int mt = 0; mt < 4; ++mt)
#pragma unroll
            for (int nt = 0; nt < 2; ++nt)
#pragma unroll
                for (int ks = 0; ks < 2; ++ks)
                    acc[mt][nt] = __builtin_amdgcn_mfma_f32_16x16x32_f16(
                        afA[mt][ks], bf0[nt][ks], acc[mt][nt], 0, 0, 0);
        __builtin_amdgcn_s_setprio(0);
        BARRIER();

        // ---- phase 1: stage A-h1(t+1); MFMA(afA,bf1) ∥ prefetch afB(t,m1)
        if (t + 1 < NT) STG(LA + (bo ^ 16384) + 8192, gA1, t + 1);
        BARRIER();
        asm volatile("s_waitcnt lgkmcnt(0)" ::: "memory");
        __builtin_amdgcn_s_setprio(1);
#pragma unroll
        for (int mt = 0; mt < 4; ++mt)
#pragma unroll
            for (int ks = 0; ks < 2; ++ks)
                afB[mt][ks] = *(const f16x8*)(pa + (mt + 4) * 1024 + foff[ks]);
#pragma unroll
        for (int mt = 0; mt < 4; ++mt)
#pragma unroll
            for (int nt = 0; nt < 2; ++nt)
#pragma unroll
                for (int ks = 0; ks < 2; ++ks)
                    acc[mt][nt + 2] = __builtin_amdgcn_mfma_f32_16x16x32_f16(
                        afA[mt][ks], bf1[nt][ks], acc[mt][nt + 2], 0, 0, 0);
        __builtin_amdgcn_s_setprio(0);
        BARRIER();

        // ---- phase 2: stage B-h0(t+2); MFMA(afB,bf1)
        if (t + 2 < NT) STG(LB + bo, gB0, t + 2);
        BARRIER();
        asm volatile("s_waitcnt lgkmcnt(0)" ::: "memory");
        __builtin_amdgcn_s_setprio(1);
#pragma unroll
        for (int mt = 0; mt < 4; ++mt)
#pragma unroll
            for (int nt = 0; nt < 2; ++nt)
#pragma unroll
                for (int ks = 0; ks < 2; ++ks)
                    acc[mt + 4][nt + 2] = __builtin_amdgcn_mfma_f32_16x16x32_f16(
                        afB[mt][ks], bf1[nt][ks], acc[mt + 4][nt + 2], 0, 0, 0);
        __builtin_amdgcn_s_setprio(0);
        BARRIER();

        // ---- phase 3: stage B-h1(t+2); vmcnt+BAR (A/B(t+1) visible);
        //      MFMA(afB,bf0) ∥ prefetch afA(t+1); THEN prefetch bf0(t+1)
        //      (bf0(t) must be consumed by the MFMA before being overwritten)
        if (t + 2 < NT) STG(LB + bo + 8192, gB1, t + 2);
        if (t + 2 < NT) { asm volatile("s_waitcnt vmcnt(4)" ::: "memory"); }
        else            { asm volatile("s_waitcnt vmcnt(0)" ::: "memory"); }
        BARRIER();
        __builtin_amdgcn_s_setprio(1);
        if (t + 1 < NT) {
#pragma unroll
            for (int mt = 0; mt < 4; ++mt)
#pragma unroll
                for (int ks = 0; ks < 2; ++ks)
                    afA[mt][ks] = *(const f16x8*)(pa1 + mt * 1024 + foff[ks]);
        }
#pragma unroll
        for (int mt = 0; mt < 4; ++mt)
#pragma unroll
            for (int nt = 0; nt < 2; ++nt)
#pragma unroll
                for (int ks = 0; ks < 2; ++ks)
                    acc[mt + 4][nt] = __builtin_amdgcn_mfma_f32_16x16x32_f16(
                        afB[mt][ks], bf0[nt][ks], acc[mt + 4][nt], 0, 0, 0);
        if (t + 1 < NT) {
#pragma unroll
            for (int nt = 0; nt < 2; ++nt)
#pragma unroll
                for (int ks = 0; ks < 2; ++ks)
                    bf0[nt][ks] = *(const f16x8*)(pb1 + nt * 1024 + foff[ks]);
        }
        __builtin_amdgcn_s_setprio(0);
        BARRIER();
    }
#undef STG

    // epilogue: row = bm + wm*128 + mt*16 + quad*4 + r, col = bn + wn*64 + nt*16 + m16
#pragma unroll
    for (int mt = 0; mt < 8; ++mt)
#pragma unroll
        for (int r = 0; r < 4; ++r) {
            int row = bm + wm * 128 + mt * 16 + quad * 4 + r;
            CT* cp = C + (size_t)row * N + bn + wn * 64 + m16;
#pragma unroll
            for (int nt = 0; nt < 4; ++nt) cp[nt * 16] = (CT)acc[mt][nt][r];
        }
}

// ---------------------------------------------------------------- RoPE (q,k only)
// Paged cache scatter+gather through an injective block_table is the identity on
// (b,s) -> skip the cache. qkv row: q 0:4096 | k 4096:5120 | v 5120:6144.
__global__ __launch_bounds__(256) void rope_qk(const f16* __restrict__ qkv,
                                               const float* __restrict__ freqs,
                                               f16* __restrict__ qh,
                                               f16* __restrict__ kk) {
    int idx  = blockIdx.x * 256 + threadIdx.x;     // B*S*40heads*64pairs
    int row  = idx / 2560;
    int p    = idx - row * 2560;
    int b    = row >> 11, s = row & 2047;
    int head = p >> 6, i = p & 63;
    const f16* src = qkv + (size_t)row * 6144 + head * 128 + 2 * i;
    float v0 = (float)src[0], v1 = (float)src[1];
    float c  = freqs[s * 128 + 2 * i];
    float sn = freqs[s * 128 + 2 * i + 1];
    float r0 = v0 * c - v1 * sn;
    float r1 = v1 * c + v0 * sn;
    f16* dst = (head < 32)
        ? qh + (((size_t)(b * 32 + head)) * 2048 + s) * 128 + 2 * i
        : kk + (((size_t)(b * 8 + head - 32)) * 2048 + s) * 128 + 2 * i;
    dst[0] = (f16)r0; dst[1] = (f16)r1;
}

// ---------------------------------------------------------------- V transpose (LDS-tiled)
__global__ __launch_bounds__(256) void transpose_v(const f16* __restrict__ qkv,
                                                   f16* __restrict__ vvt) {
    __shared__ f16 T[64][72];
    const int st = blockIdx.x, dt = blockIdx.y;
    const int b = blockIdx.z >> 3, kvh = blockIdx.z & 7;
    const int tid = threadIdx.x;
    const int sr = tid >> 3, c8 = (tid & 7) * 8;
#pragma unroll
    for (int rep = 0; rep < 2; ++rep) {
        int sl = rep * 32 + sr;
        *(f16x8*)&T[sl][c8] =
            *(const f16x8*)(qkv + (size_t)(b * 2048 + st * 64 + sl) * 6144
                            + 5120 + kvh * 128 + dt * 64 + c8);
    }
    __syncthreads();
#pragma unroll
    for (int rep = 0; rep < 2; ++rep) {
        int dl = rep * 32 + sr;
        f16x8 v;
#pragma unroll
        for (int j = 0; j < 8; ++j) v[j] = T[c8 + j][dl];
        *(f16x8*)(vvt + (((size_t)(b * 8 + kvh)) * 128 + dt * 64 + dl) * 2048
                  + st * 64 + c8) = v;
    }
}

// ---------------------------------------------------------------- flash attention v6
// v5 body restructured to 512-thread / 8-wave blocks, QBLK=128:
//  * 8 waves (16 q-rows each) share ONE K/V staging -> staging bytes and
//    barrier events per q-row HALVE (2 blocks/CU x 34 ktiles replaces
//    4 blocks/CU x 33).
//  * Ps gets a DEDICATED LDS region (no Ks overlay) -> P write/read is
//    wave-private -> the third per-ktile barrier is deleted (2 remain).
//  * LDS 54.3 KB -> 2 blocks/CU x 8 waves = 16 waves/CU (occupancy unchanged);
//    grid (8,32,2)=512 = exactly 2/CU; heavy-first pairing qt in {15-p, p}
//    gives every block exactly 34 ktiles.
// Per-wave math (fragments, log2-softmax, exact defer-rescale, T14 async
// reg-staging with undrained vmcnt across barriers) identical to v5.
__global__ __launch_bounds__(512) void attn_fused(const f16* __restrict__ qh,
                                                  const f16* __restrict__ kk,
                                                  const f16* __restrict__ vvt,
                                                  const int* __restrict__ seqlens,
                                                  f16* __restrict__ out) {
    __shared__ f16 Ks[64 * 136];     // [key][d] stride 136
    __shared__ f16 Vs[128][72];      // [d][key] stride 72 (2-way free)
    __shared__ f16 Ps[128 * 72];     // [qrow][key] stride 72, wave-private rows
    const int pair = blockIdx.x;     // 0..7
    const int h = blockIdx.y, b = blockIdx.z;
    const int kvh = h >> 2;
    const int tid = threadIdx.x, wave = tid >> 6, lane = tid & 63;
    const int quad = lane >> 4, m16 = lane & 15;

    const int seqlen = seqlens[b];
    const f16* kbp = kk  + ((size_t)(b * 8 + kvh) * 2048) * 128;
    const f16* vbp = vvt + ((size_t)(b * 8 + kvh) * 128) * 2048;

    // scale * log2(e): softmax runs in the log2 domain
    const float SCL2 = 0.08838834764831845f * 1.4426950408889634f;

    for (int half = 0; half < 2; ++half) {
        const int qt = half ? pair : (15 - pair);   // heavy tile first
        const int qbase = qt * 128;
        const int qw = qbase + wave * 16;

        const f16* qptr = qh + (((size_t)(b * 32 + h)) * 2048 + qw + m16) * 128;
        f16x8 qf[4];
#pragma unroll
        for (int c = 0; c < 4; ++c) qf[c] = *(const f16x8*)(qptr + c * 32 + quad * 8);

        float m_i[4], l_i[4];
        f32x4 oacc[8];
#pragma unroll
        for (int r = 0; r < 4; ++r) { m_i[r] = NEG_INF; l_i[r] = 0.f; }
#pragma unroll
        for (int dt = 0; dt < 8; ++dt)
#pragma unroll
            for (int e = 0; e < 4; ++e) oacc[dt][e] = 0.f;

        int kmax = qbase + 128; if (seqlen < kmax) kmax = seqlen;

        // prefetch tile 0 into registers (512 threads: 2 chunks each of K and V)
        f16x8 gk[2], gv[2];
#pragma unroll
        for (int it = 0; it < 2; ++it) {
            int g = it * 512 + tid;
            gk[it] = *(const f16x8*)(kbp + (size_t)(g >> 4) * 128 + (g & 15) * 8);
            gv[it] = *(const f16x8*)(vbp + (size_t)(g >> 3) * 2048 + (g & 7) * 8);
        }

        for (int kt = 0; kt < kmax; kt += 64) {
            BARRIER();   // all waves' Ks/Vs reads of prev iter are complete
            // reg -> LDS (K tile: 64 keys x 128 d; V^T tile: 128 d x 64 keys)
#pragma unroll
            for (int it = 0; it < 2; ++it) {
                int g = it * 512 + tid;
                *(f16x8*)&Ks[(g >> 4) * 136 + (g & 15) * 8] = gk[it];
                *(f16x8*)&Vs[g >> 3][(g & 7) * 8] = gv[it];
            }
            // issue next tile's loads; they stay in flight across the barrier
            if (kt + 64 < kmax) {
#pragma unroll
                for (int it = 0; it < 2; ++it) {
                    int g = it * 512 + tid;
                    gk[it] = *(const f16x8*)(kbp + (size_t)(kt + 64 + (g >> 4)) * 128 + (g & 15) * 8);
                    gv[it] = *(const f16x8*)(vbp + (size_t)(g >> 3) * 2048 + (kt + 64) + (g & 7) * 8);
                }
            }
            asm volatile("s_waitcnt lgkmcnt(0)" ::: "memory");  // LDS writes visible
            BARRIER();                                          // vmcnt NOT drained

            // S = Q K^T
            f32x4 sc[4];
#pragma unroll
            for (int nt = 0; nt < 4; ++nt) {
                f32x4 s = {0.f, 0.f, 0.f, 0.f};
#pragma unroll
                for (int c = 0; c < 4; ++c) {
                    f16x8 kf = *(const f16x8*)&Ks[(nt * 16 + m16) * 136 + c * 32 + quad * 8];
                    s = __builtin_amdgcn_mfma_f32_16x16x32_f16(qf[c], kf, s, 0, 0, 0);
                }
                sc[nt] = s;
            }

            // scale + mask (log2 domain) + online softmax
            float sv[4][4];
            float mt[4] = {NEG_INF, NEG_INF, NEG_INF, NEG_INF};
#pragma unroll
            for (int nt = 0; nt < 4; ++nt) {
                int kpos = kt + nt * 16 + m16;
#pragma unroll
                for (int r = 0; r < 4; ++r) {
                    int qpos = qw + quad * 4 + r;
                    float sx = sc[nt][r] * SCL2;
                    sx = (kpos <= qpos && kpos < seqlen) ? sx : NEG_INF;
                    sv[nt][r] = sx;
                    mt[r] = fmaxf(mt[r], sx);
                }
            }
#pragma unroll
            for (int off = 1; off < 16; off <<= 1)
#pragma unroll
                for (int r = 0; r < 4; ++r)
                    mt[r] = fmaxf(mt[r], __shfl_xor(mt[r], off, 64));

            // exact defer: mt/m_i are wave-uniform -> uniform branch; skip the
            // alpha+rescale pass entirely when no row's max grew (alpha==1).
            float mm[4];
            bool grow = (mt[0] > m_i[0]) | (mt[1] > m_i[1]) |
                        (mt[2] > m_i[2]) | (mt[3] > m_i[3]);
            if (grow) {
#pragma unroll
                for (int r = 0; r < 4; ++r) {
                    float mo = m_i[r];
                    float mn = fmaxf(mo, mt[r]);
                    float mmr = fmaxf(mn, -1e30f);
                    float a = EXP2F(mo - mmr);
                    m_i[r] = mn;
                    mm[r] = mmr;
                    l_i[r] *= a;
#pragma unroll
                    for (int dt = 0; dt < 8; ++dt) oacc[dt][r] *= a;
                }
            } else {
#pragma unroll
                for (int r = 0; r < 4; ++r) mm[r] = fmaxf(m_i[r], -1e30f);
            }
            float rs[4] = {0.f, 0.f, 0.f, 0.f};
#pragma unroll
            for (int nt = 0; nt < 4; ++nt)
#pragma unroll
                for (int r = 0; r < 4; ++r) {
                    float pv = EXP2F(sv[nt][r] - mm[r]);
                    sv[nt][r] = pv;
                    rs[r] += pv;
                }
#pragma unroll
            for (int off = 1; off < 16; off <<= 1)
#pragma unroll
                for (int r = 0; r < 4; ++r) rs[r] += __shfl_xor(rs[r], off, 64);
#pragma unroll
            for (int r = 0; r < 4; ++r) l_i[r] += rs[r];

            // P: C-layout regs -> WAVE-PRIVATE Ps rows -> A-layout fragments.
            // No barrier: rows [wave*16, wave*16+16) are touched only by this
            // wave; compiler orders the ds_write -> ds_read via lgkmcnt.
#pragma unroll
            for (int nt = 0; nt < 4; ++nt)
#pragma unroll
                for (int r = 0; r < 4; ++r)
                    Ps[(wave * 16 + quad * 4 + r) * 72 + nt * 16 + m16] = (f16)sv[nt][r];

            f16x8 pf[2];
#pragma unroll
            for (int c = 0; c < 2; ++c)
                pf[c] = *(const f16x8*)&Ps[(wave * 16 + m16) * 72 + c * 32 + quad * 8];
#pragma unroll
            for (int dt = 0; dt < 8; ++dt)
#pragma unroll
                for (int c = 0; c < 2; ++c) {
                    f16x8 vf = *(const f16x8*)&Vs[dt * 16 + m16][c * 32 + quad * 8];
                    oacc[dt] = __builtin_amdgcn_mfma_f32_16x16x32_f16(pf[c], vf, oacc[dt], 0, 0, 0);
                }
        }

        // normalize + write [B,S,NH*HD]
#pragma unroll
        for (int r = 0; r < 4; ++r) {
            int qpos = qw + quad * 4 + r;
            float inv = 1.0f / l_i[r];
            f16* op = out + ((size_t)b * 2048 + qpos) * 4096 + h * 128;
#pragma unroll
            for (int dt = 0; dt < 8; ++dt)
                op[dt * 16 + m16] = (f16)(oacc[dt][r] * inv);
        }
        // next half's k-loop starts with BARRIER(), protecting LDS reuse
    }
}

// ---------------------------------------------------------------- launch
extern "C" void kernel_launch(void* const* d_in, const int* in_sizes, int n_in,
                              void* d_out, int out_size, void* d_ws, size_t ws_size,
                              hipStream_t stream) {
    const float* x     = (const float*)d_in[0];   // [2,2048,4096]
    const float* wqkv  = (const float*)d_in[1];   // [6144,4096]
    const float* wo    = (const float*)d_in[2];   // [4096,4096]
    const float* freqs = (const float*)d_in[3];   // [2048,1,64,2]
    const int*   seql  = (const int*)d_in[7];     // [2]
    float* out = (float*)d_out;

    char* ws = (char*)d_ws;
    size_t o = 0;
    f16* xh    = (f16*)(ws + o); o += (size_t)4096 * 4096 * 2;   // reused as attn_h
    f16* wqkvh = (f16*)(ws + o); o += (size_t)6144 * 4096 * 2;
    f16* woh   = (f16*)(ws + o); o += (size_t)4096 * 4096 * 2;
    f16* qkvh  = (f16*)(ws + o); o += (size_t)4096 * 6144 * 2;
    f16* qhp   = (f16*)(ws + o); o += (size_t)4096 * 4096 * 2;
    f16* kkp   = (f16*)(ws + o); o += (size_t)4096 * 8 * 128 * 2;
    f16* vvt   = (f16*)(ws + o); o += (size_t)4096 * 8 * 128 * 2;
    f16* attnh = xh;  // xh dead after GEMM1

    cvt_f32_f16<<<16384, 256, 0, stream>>>(x, xh, 4194304);
    cvt_f32_f16<<<24576, 256, 0, stream>>>(wqkv, wqkvh, 6291456);
    cvt_f32_f16<<<16384, 256, 0, stream>>>(wo, woh, 4194304);

    gemm256<f16><<<384, 512, 0, stream>>>(xh, wqkvh, qkvh, 4096, 6144, 4096);

    rope_qk<<<40960, 256, 0, stream>>>(qkvh, freqs, qhp, kkp);
    transpose_v<<<dim3(32, 2, 16), 256, 0, stream>>>(qkvh, vvt);

    attn_fused<<<dim3(8, 32, 2), 512, 0, stream>>>(qhp, kkp, vvt, seql, attnh);

    gemm256<float><<<256, 512, 0, stream>>>(attnh, woh, out, 4096, 4096, 4096);
}

// Round 10
// 806.828 us; speedup vs baseline: 1.0510x; 1.0290x over previous
//
#include <hip/hip_runtime.h>
#include <hip/hip_fp16.h>

typedef _Float16 f16;
typedef _Float16 f16x4 __attribute__((ext_vector_type(4)));
typedef _Float16 f16x8 __attribute__((ext_vector_type(8)));
typedef float    f32x4 __attribute__((ext_vector_type(4)));

#define NEG_INF (-__builtin_inff())
#define AS1 __attribute__((address_space(1)))
#define AS3 __attribute__((address_space(3)))
#define GLOAD_LDS16(g, l) \
    __builtin_amdgcn_global_load_lds((AS1 const void*)(g), (AS3 void*)(l), 16, 0, 0)
// v_exp_f32 computes 2^x; this builtin maps to it directly (NOT __exp2f, which
// collides with glibc math.h and does not exist as a HIP device function).
#define EXP2F(x) __builtin_amdgcn_exp2f(x)
// s_barrier is IntrNoMem at IR level: bracket with compile-time fences so no
// memory op (ds_read / global_load_lds) can be scheduled across a phase edge.
#define BARRIER() do { asm volatile("" ::: "memory"); \
                       __builtin_amdgcn_s_barrier(); \
                       asm volatile("" ::: "memory"); } while (0)

// ---------------------------------------------------------------- converts
__global__ __launch_bounds__(256) void cvt_f32_f16(const float* __restrict__ in,
                                                   f16* __restrict__ out, int n4) {
    int i = blockIdx.x * 256 + threadIdx.x;
    if (i >= n4) return;
    float4 v = ((const float4*)in)[i];
    f16x4 h = {(f16)v.x, (f16)v.y, (f16)v.z, (f16)v.w};
    ((f16x4*)out)[i] = h;
}

// ---------------------------------------------------------------- GEMM C = A * Bt^T
// FROZEN (r8, measured 258 us, MfmaUtil ~34): r3 barrier/staging ledger +
// fragment prefetch under MFMA clusters. Three scheduling attempts (r4 deeper
// vmcnt, r6/r8 read pipelining) were null or negative: with 8 waves / 4 SIMDs
// the cross-wave overlap already hides LDS reads; ~34% is this structure's
// ceiling. Do not touch.
template <typename CT>
__global__ __launch_bounds__(512) void gemm256(const f16* __restrict__ A,
                                               const f16* __restrict__ Bt,
                                               CT* __restrict__ C,
                                               int M, int N, int K) {
    __shared__ __align__(16) f16 smem[65536];     // LA[2][2][8192] | LB[2][2][8192]
    f16* LA = smem;
    f16* LB = smem + 32768;

    const int tid  = threadIdx.x;
    const int wave = tid >> 6, lane = tid & 63;
    const int quad = lane >> 4, m16 = lane & 15;
    const int wm = wave >> 2, wn = wave & 3;

    // bijective XCD-aware block swizzle (m204 form)
    const int ntn = N >> 8;
    const int nwg = (M >> 8) * ntn;
    const int q8 = nwg >> 3, r8 = nwg & 7;
    const int xcd = blockIdx.x & 7, idx = blockIdx.x >> 3;
    const int swz = (xcd < r8 ? xcd * (q8 + 1) : r8 * (q8 + 1) + (xcd - r8) * q8) + idx;
    const int bm = (swz / ntn) << 8;
    const int bn = (swz % ntn) << 8;

    // staging: thread tid fills linear LDS elems tid*8 (+4096 for rows 64..127);
    // source column-granule XOR-pre-permuted so swizzled reads see logical data.
    const int rowW = tid >> 3;                         // 0..63
    const int gsrc = (tid & 7) ^ (rowW & 7);
    const f16* gA0 = A  + (size_t)(bm + rowW) * K + gsrc * 8;
    const f16* gA1 = A  + (size_t)(bm + 128 + rowW) * K + gsrc * 8;
    const f16* gB0 = Bt + (size_t)(bn + rowW) * K + gsrc * 8;
    const f16* gB1 = Bt + (size_t)(bn + 128 + rowW) * K + gsrc * 8;
    const size_t rstep = (size_t)64 * K;
    const int lw = wave * 512;                         // wave-uniform LDS elem offset

#define STG(dstbase, gp, kt) do { \
    GLOAD_LDS16((gp) + (size_t)(kt) * 64,         (dstbase) + lw); \
    GLOAD_LDS16((gp) + (size_t)(kt) * 64 + rstep, (dstbase) + lw + 4096); } while (0)

    // fragment LDS offsets (elems): row*64 + (((ks*4+quad) ^ (row&7))*8
    int foff[2];
#pragma unroll
    for (int ks = 0; ks < 2; ++ks)
        foff[ks] = (((ks << 2) | quad) ^ (m16 & 7)) * 8;
    const int arow = wm * 8192 + m16 * 64;             // + mt*1024
    const int brow = (wn >> 1) * 8192 + (wn & 1) * 4096 + m16 * 64;   // + nt*1024

    f32x4 acc[8][4];
#pragma unroll
    for (int i = 0; i < 8; ++i)
#pragma unroll
        for (int j = 0; j < 4; ++j)
#pragma unroll
            for (int e = 0; e < 4; ++e) acc[i][j][e] = 0.f;

    const int NT = K >> 6;

    // prologue: tile0 {A0,A1,B0,B1} + tile1 {B0,B1}; vmcnt(4) lands tile0;
    // then prefetch tile0's ph0 fragments (afA m0 + bf0) before entering loop.
    STG(LA, gA0, 0); STG(LA + 8192, gA1, 0);
    STG(LB, gB0, 0); STG(LB + 8192, gB1, 0);
    STG(LB + 16384, gB0, 1); STG(LB + 16384 + 8192, gB1, 1);
    asm volatile("s_waitcnt vmcnt(4)" ::: "memory");
    BARRIER();

    f16x8 afA[4][2], afB[4][2], bf0[2][2], bf1[2][2];
#pragma unroll
    for (int mt = 0; mt < 4; ++mt)
#pragma unroll
        for (int ks = 0; ks < 2; ++ks)
            afA[mt][ks] = *(const f16x8*)(LA + arow + mt * 1024 + foff[ks]);
#pragma unroll
    for (int nt = 0; nt < 2; ++nt)
#pragma unroll
        for (int ks = 0; ks < 2; ++ks)
            bf0[nt][ks] = *(const f16x8*)(LB + brow + nt * 1024 + foff[ks]);

    for (int t = 0; t < NT; ++t) {
        const int bo = (t & 1) * 16384;
        const f16* pa = LA + bo + arow;
        const f16* pb = LB + bo + brow;
        const f16* pa1 = LA + (bo ^ 16384) + arow;     // next tile's buffer
        const f16* pb1 = LB + (bo ^ 16384) + brow;

        // ---- phase 0: stage A-h0(t+1); MFMA(afA,bf0) ∥ prefetch bf1(t)
        if (t + 1 < NT) STG(LA + (bo ^ 16384), gA0, t + 1);
        BARRIER();
        asm volatile("s_waitcnt lgkmcnt(0)" ::: "memory");
        __builtin_amdgcn_s_setprio(1);
#pragma unroll
        for (int nt = 0; nt < 2; ++nt)
#pragma unroll
            for (int ks = 0; ks < 2; ++ks)
                bf1[nt][ks] = *(const f16x8*)(pb + (nt + 2) * 1024 + foff[ks]);
#pragma unroll
        for (int mt = 0; mt < 4; ++mt)
#pragma unroll
            for (int nt = 0; nt < 2; ++nt)
#pragma unroll
                for (int ks = 0; ks < 2; ++ks)
                    acc[mt][nt] = __builtin_amdgcn_mfma_f32_16x16x32_f16(
                        afA[mt][ks], bf0[nt][ks], acc[mt][nt], 0, 0, 0);
        __builtin_amdgcn_s_setprio(0);
        BARRIER();

        // ---- phase 1: stage A-h1(t+1); MFMA(afA,bf1) ∥ prefetch afB(t,m1)
        if (t + 1 < NT) STG(LA + (bo ^ 16384) + 8192, gA1, t + 1);
        BARRIER();
        asm volatile("s_waitcnt lgkmcnt(0)" ::: "memory");
        __builtin_amdgcn_s_setprio(1);
#pragma unroll
        for (int mt = 0; mt < 4; ++mt)
#pragma unroll
            for (int ks = 0; ks < 2; ++ks)
                afB[mt][ks] = *(const f16x8*)(pa + (mt + 4) * 1024 + foff[ks]);
#pragma unroll
        for (int mt = 0; mt < 4; ++mt)
#pragma unroll
            for (int nt = 0; nt < 2; ++nt)
#pragma unroll
                for (int ks = 0; ks < 2; ++ks)
                    acc[mt][nt + 2] = __builtin_amdgcn_mfma_f32_16x16x32_f16(
                        afA[mt][ks], bf1[nt][ks], acc[mt][nt + 2], 0, 0, 0);
        __builtin_amdgcn_s_setprio(0);
        BARRIER();

        // ---- phase 2: stage B-h0(t+2); MFMA(afB,bf1)
        if (t + 2 < NT) STG(LB + bo, gB0, t + 2);
        BARRIER();
        asm volatile("s_waitcnt lgkmcnt(0)" ::: "memory");
        __builtin_amdgcn_s_setprio(1);
#pragma unroll
        for (int mt = 0; mt < 4; ++mt)
#pragma unroll
            for (int nt = 0; nt < 2; ++nt)
#pragma unroll
                for (int ks = 0; ks < 2; ++ks)
                    acc[mt + 4][nt + 2] = __builtin_amdgcn_mfma_f32_16x16x32_f16(
                        afB[mt][ks], bf1[nt][ks], acc[mt + 4][nt + 2], 0, 0, 0);
        __builtin_amdgcn_s_setprio(0);
        BARRIER();

        // ---- phase 3: stage B-h1(t+2); vmcnt+BAR (A/B(t+1) visible);
        //      MFMA(afB,bf0) ∥ prefetch afA(t+1); THEN prefetch bf0(t+1)
        //      (bf0(t) must be consumed by the MFMA before being overwritten)
        if (t + 2 < NT) STG(LB + bo + 8192, gB1, t + 2);
        if (t + 2 < NT) { asm volatile("s_waitcnt vmcnt(4)" ::: "memory"); }
        else            { asm volatile("s_waitcnt vmcnt(0)" ::: "memory"); }
        BARRIER();
        __builtin_amdgcn_s_setprio(1);
        if (t + 1 < NT) {
#pragma unroll
            for (int mt = 0; mt < 4; ++mt)
#pragma unroll
                for (int ks = 0; ks < 2; ++ks)
                    afA[mt][ks] = *(const f16x8*)(pa1 + mt * 1024 + foff[ks]);
        }
#pragma unroll
        for (int mt = 0; mt < 4; ++mt)
#pragma unroll
            for (int nt = 0; nt < 2; ++nt)
#pragma unroll
                for (int ks = 0; ks < 2; ++ks)
                    acc[mt + 4][nt] = __builtin_amdgcn_mfma_f32_16x16x32_f16(
                        afB[mt][ks], bf0[nt][ks], acc[mt + 4][nt], 0, 0, 0);
        if (t + 1 < NT) {
#pragma unroll
            for (int nt = 0; nt < 2; ++nt)
#pragma unroll
                for (int ks = 0; ks < 2; ++ks)
                    bf0[nt][ks] = *(const f16x8*)(pb1 + nt * 1024 + foff[ks]);
        }
        __builtin_amdgcn_s_setprio(0);
        BARRIER();
    }
#undef STG

    // epilogue: row = bm + wm*128 + mt*16 + quad*4 + r, col = bn + wn*64 + nt*16 + m16
#pragma unroll
    for (int mt = 0; mt < 8; ++mt)
#pragma unroll
        for (int r = 0; r < 4; ++r) {
            int row = bm + wm * 128 + mt * 16 + quad * 4 + r;
            CT* cp = C + (size_t)row * N + bn + wn * 64 + m16;
#pragma unroll
            for (int nt = 0; nt < 4; ++nt) cp[nt * 16] = (CT)acc[mt][nt][r];
        }
}

// ---------------------------------------------------------------- RoPE (q,k only)
// Paged cache scatter+gather through an injective block_table is the identity on
// (b,s) -> skip the cache. qkv row: q 0:4096 | k 4096:5120 | v 5120:6144.
__global__ __launch_bounds__(256) void rope_qk(const f16* __restrict__ qkv,
                                               const float* __restrict__ freqs,
                                               f16* __restrict__ qh,
                                               f16* __restrict__ kk) {
    int idx  = blockIdx.x * 256 + threadIdx.x;     // B*S*40heads*64pairs
    int row  = idx / 2560;
    int p    = idx - row * 2560;
    int b    = row >> 11, s = row & 2047;
    int head = p >> 6, i = p & 63;
    const f16* src = qkv + (size_t)row * 6144 + head * 128 + 2 * i;
    float v0 = (float)src[0], v1 = (float)src[1];
    float c  = freqs[s * 128 + 2 * i];
    float sn = freqs[s * 128 + 2 * i + 1];
    float r0 = v0 * c - v1 * sn;
    float r1 = v1 * c + v0 * sn;
    f16* dst = (head < 32)
        ? qh + (((size_t)(b * 32 + head)) * 2048 + s) * 128 + 2 * i
        : kk + (((size_t)(b * 8 + head - 32)) * 2048 + s) * 128 + 2 * i;
    dst[0] = (f16)r0; dst[1] = (f16)r1;
}

// ---------------------------------------------------------------- V transpose (LDS-tiled)
__global__ __launch_bounds__(256) void transpose_v(const f16* __restrict__ qkv,
                                                   f16* __restrict__ vvt) {
    __shared__ f16 T[64][72];
    const int st = blockIdx.x, dt = blockIdx.y;
    const int b = blockIdx.z >> 3, kvh = blockIdx.z & 7;
    const int tid = threadIdx.x;
    const int sr = tid >> 3, c8 = (tid & 7) * 8;
#pragma unroll
    for (int rep = 0; rep < 2; ++rep) {
        int sl = rep * 32 + sr;
        *(f16x8*)&T[sl][c8] =
            *(const f16x8*)(qkv + (size_t)(b * 2048 + st * 64 + sl) * 6144
                            + 5120 + kvh * 128 + dt * 64 + c8);
    }
    __syncthreads();
#pragma unroll
    for (int rep = 0; rep < 2; ++rep) {
        int dl = rep * 32 + sr;
        f16x8 v;
#pragma unroll
        for (int j = 0; j < 8; ++j) v[j] = T[c8 + j][dl];
        *(f16x8*)(vvt + (((size_t)(b * 8 + kvh)) * 128 + dt * 64 + dl) * 2048
                  + st * 64 + c8) = v;
    }
}

// ---------------------------------------------------------------- flash attention v7
// v6 structure (512 thr / 8 waves, QBLK=128, 2 barriers/ktile, T14 async
// staging) + three VALU cuts in the softmax hot loop:
//  * Q pre-scaled by scale*log2e at load -> no per-ktile multiply.
//  * mask-skip on non-diagonal tiles (wave-uniform: kt+63<=qw && kt+64<=seqlen
//    implies every kpos <= every qpos and in-range).
//  * per-lane PARTIAL l_i (each lane sums its m16 kpos-slice; alpha-rescale is
//    uniform across m16 so partials stay consistent); ONE shfl reduce at the
//    epilogue replaces 16 shfl + 16 add per ktile.
__global__ __launch_bounds__(512) void attn_fused(const f16* __restrict__ qh,
                                                  const f16* __restrict__ kk,
                                                  const f16* __restrict__ vvt,
                                                  const int* __restrict__ seqlens,
                                                  f16* __restrict__ out) {
    __shared__ f16 Ks[64 * 136];     // [key][d] stride 136
    __shared__ f16 Vs[128][72];      // [d][key] stride 72 (2-way free)
    __shared__ f16 Ps[128 * 72];     // [qrow][key] stride 72, wave-private rows
    const int pair = blockIdx.x;     // 0..7
    const int h = blockIdx.y, b = blockIdx.z;
    const int kvh = h >> 2;
    const int tid = threadIdx.x, wave = tid >> 6, lane = tid & 63;
    const int quad = lane >> 4, m16 = lane & 15;

    const int seqlen = seqlens[b];
    const f16* kbp = kk  + ((size_t)(b * 8 + kvh) * 2048) * 128;
    const f16* vbp = vvt + ((size_t)(b * 8 + kvh) * 128) * 2048;

    // scale * log2(e): softmax runs in the log2 domain, folded into Q.
    const float SCL2 = 0.08838834764831845f * 1.4426950408889634f;

    for (int half = 0; half < 2; ++half) {
        const int qt = half ? pair : (15 - pair);   // heavy tile first
        const int qbase = qt * 128;
        const int qw = qbase + wave * 16;

        const f16* qptr = qh + (((size_t)(b * 32 + h)) * 2048 + qw + m16) * 128;
        f16x8 qf[4];
#pragma unroll
        for (int c = 0; c < 4; ++c) {
            qf[c] = *(const f16x8*)(qptr + c * 32 + quad * 8);
#pragma unroll
            for (int j = 0; j < 8; ++j)
                qf[c][j] = (f16)((float)qf[c][j] * SCL2);
        }

        float m_i[4], l_i[4];
        f32x4 oacc[8];
#pragma unroll
        for (int r = 0; r < 4; ++r) { m_i[r] = NEG_INF; l_i[r] = 0.f; }
#pragma unroll
        for (int dt = 0; dt < 8; ++dt)
#pragma unroll
            for (int e = 0; e < 4; ++e) oacc[dt][e] = 0.f;

        int kmax = qbase + 128; if (seqlen < kmax) kmax = seqlen;

        // prefetch tile 0 into registers (512 threads: 2 chunks each of K and V)
        f16x8 gk[2], gv[2];
#pragma unroll
        for (int it = 0; it < 2; ++it) {
            int g = it * 512 + tid;
            gk[it] = *(const f16x8*)(kbp + (size_t)(g >> 4) * 128 + (g & 15) * 8);
            gv[it] = *(const f16x8*)(vbp + (size_t)(g >> 3) * 2048 + (g & 7) * 8);
        }

        for (int kt = 0; kt < kmax; kt += 64) {
            BARRIER();   // all waves' Ks/Vs reads of prev iter are complete
            // reg -> LDS (K tile: 64 keys x 128 d; V^T tile: 128 d x 64 keys)
#pragma unroll
            for (int it = 0; it < 2; ++it) {
                int g = it * 512 + tid;
                *(f16x8*)&Ks[(g >> 4) * 136 + (g & 15) * 8] = gk[it];
                *(f16x8*)&Vs[g >> 3][(g & 7) * 8] = gv[it];
            }
            // issue next tile's loads; they stay in flight across the barrier
            if (kt + 64 < kmax) {
#pragma unroll
                for (int it = 0; it < 2; ++it) {
                    int g = it * 512 + tid;
                    gk[it] = *(const f16x8*)(kbp + (size_t)(kt + 64 + (g >> 4)) * 128 + (g & 15) * 8);
                    gv[it] = *(const f16x8*)(vbp + (size_t)(g >> 3) * 2048 + (kt + 64) + (g & 7) * 8);
                }
            }
            asm volatile("s_waitcnt lgkmcnt(0)" ::: "memory");  // LDS writes visible
            BARRIER();                                          // vmcnt NOT drained

            // S = Q K^T (pre-scaled, log2 domain)
            f32x4 sc[4];
#pragma unroll
            for (int nt = 0; nt < 4; ++nt) {
                f32x4 s = {0.f, 0.f, 0.f, 0.f};
#pragma unroll
                for (int c = 0; c < 4; ++c) {
                    f16x8 kf = *(const f16x8*)&Ks[(nt * 16 + m16) * 136 + c * 32 + quad * 8];
                    s = __builtin_amdgcn_mfma_f32_16x16x32_f16(qf[c], kf, s, 0, 0, 0);
                }
                sc[nt] = s;
            }

            // mask only on diagonal/partial tiles (wave-uniform branch)
            float sv[4][4];
            float mt[4] = {NEG_INF, NEG_INF, NEG_INF, NEG_INF};
            if (kt + 63 <= qw && kt + 64 <= seqlen) {
#pragma unroll
                for (int nt = 0; nt < 4; ++nt)
#pragma unroll
                    for (int r = 0; r < 4; ++r) {
                        float sx = sc[nt][r];
                        sv[nt][r] = sx;
                        mt[r] = fmaxf(mt[r], sx);
                    }
            } else {
#pragma unroll
                for (int nt = 0; nt < 4; ++nt) {
                    int kpos = kt + nt * 16 + m16;
#pragma unroll
                    for (int r = 0; r < 4; ++r) {
                        int qpos = qw + quad * 4 + r;
                        float sx = sc[nt][r];
                        sx = (kpos <= qpos && kpos < seqlen) ? sx : NEG_INF;
                        sv[nt][r] = sx;
                        mt[r] = fmaxf(mt[r], sx);
                    }
                }
            }
#pragma unroll
            for (int off = 1; off < 16; off <<= 1)
#pragma unroll
                for (int r = 0; r < 4; ++r)
                    mt[r] = fmaxf(mt[r], __shfl_xor(mt[r], off, 64));

            // exact defer: skip alpha+rescale entirely when no row's max grew
            // (alpha==1). mt/m_i uniform across m16; branch diverges only
            // across quad groups (both paths per-lane correct).
            float mm[4];
            bool grow = (mt[0] > m_i[0]) | (mt[1] > m_i[1]) |
                        (mt[2] > m_i[2]) | (mt[3] > m_i[3]);
            if (grow) {
#pragma unroll
                for (int r = 0; r < 4; ++r) {
                    float mo = m_i[r];
                    float mn = fmaxf(mo, mt[r]);
                    float mmr = fmaxf(mn, -1e30f);
                    float a = EXP2F(mo - mmr);
                    m_i[r] = mn;
                    mm[r] = mmr;
                    l_i[r] *= a;     // per-lane PARTIAL; a uniform across m16
#pragma unroll
                    for (int dt = 0; dt < 8; ++dt) oacc[dt][r] *= a;
                }
            } else {
#pragma unroll
                for (int r = 0; r < 4; ++r) mm[r] = fmaxf(m_i[r], -1e30f);
            }
            // per-lane partial row-sum: no cross-lane reduce here (epilogue)
#pragma unroll
            for (int nt = 0; nt < 4; ++nt)
#pragma unroll
                for (int r = 0; r < 4; ++r) {
                    float pv = EXP2F(sv[nt][r] - mm[r]);
                    sv[nt][r] = pv;
                    l_i[r] += pv;
                }

            // P: C-layout regs -> WAVE-PRIVATE Ps rows -> A-layout fragments.
            // No barrier: rows [wave*16, wave*16+16) are touched only by this
            // wave; compiler orders the ds_write -> ds_read via lgkmcnt.
#pragma unroll
            for (int nt = 0; nt < 4; ++nt)
#pragma unroll
                for (int r = 0; r < 4; ++r)
                    Ps[(wave * 16 + quad * 4 + r) * 72 + nt * 16 + m16] = (f16)sv[nt][r];

            f16x8 pf[2];
#pragma unroll
            for (int c = 0; c < 2; ++c)
                pf[c] = *(const f16x8*)&Ps[(wave * 16 + m16) * 72 + c * 32 + quad * 8];
#pragma unroll
            for (int dt = 0; dt < 8; ++dt)
#pragma unroll
                for (int c = 0; c < 2; ++c) {
                    f16x8 vf = *(const f16x8*)&Vs[dt * 16 + m16][c * 32 + quad * 8];
                    oacc[dt] = __builtin_amdgcn_mfma_f32_16x16x32_f16(pf[c], vf, oacc[dt], 0, 0, 0);
                }
        }

        // epilogue: ONE cross-lane reduce of the partial l_i, then normalize
#pragma unroll
        for (int off = 1; off < 16; off <<= 1)
#pragma unroll
            for (int r = 0; r < 4; ++r) l_i[r] += __shfl_xor(l_i[r], off, 64);
#pragma unroll
        for (int r = 0; r < 4; ++r) {
            int qpos = qw + quad * 4 + r;
            float inv = 1.0f / l_i[r];
            f16* op = out + ((size_t)b * 2048 + qpos) * 4096 + h * 128;
#pragma unroll
            for (int dt = 0; dt < 8; ++dt)
                op[dt * 16 + m16] = (f16)(oacc[dt][r] * inv);
        }
        // next half's k-loop starts with BARRIER(), protecting LDS reuse
    }
}

// ---------------------------------------------------------------- launch
extern "C" void kernel_launch(void* const* d_in, const int* in_sizes, int n_in,
                              void* d_out, int out_size, void* d_ws, size_t ws_size,
                              hipStream_t stream) {
    const float* x     = (const float*)d_in[0];   // [2,2048,4096]
    const float* wqkv  = (const float*)d_in[1];   // [6144,4096]
    const float* wo    = (const float*)d_in[2];   // [4096,4096]
    const float* freqs = (const float*)d_in[3];   // [2048,1,64,2]
    const int*   seql  = (const int*)d_in[7];     // [2]
    float* out = (float*)d_out;

    char* ws = (char*)d_ws;
    size_t o = 0;
    f16* xh    = (f16*)(ws + o); o += (size_t)4096 * 4096 * 2;   // reused as attn_h
    f16* wqkvh = (f16*)(ws + o); o += (size_t)6144 * 4096 * 2;
    f16* woh   = (f16*)(ws + o); o += (size_t)4096 * 4096 * 2;
    f16* qkvh  = (f16*)(ws + o); o += (size_t)4096 * 6144 * 2;
    f16* qhp   = (f16*)(ws + o); o += (size_t)4096 * 4096 * 2;
    f16* kkp   = (f16*)(ws + o); o += (size_t)4096 * 8 * 128 * 2;
    f16* vvt   = (f16*)(ws + o); o += (size_t)4096 * 8 * 128 * 2;
    f16* attnh = xh;  // xh dead after GEMM1

    cvt_f32_f16<<<16384, 256, 0, stream>>>(x, xh, 4194304);
    cvt_f32_f16<<<24576, 256, 0, stream>>>(wqkv, wqkvh, 6291456);
    cvt_f32_f16<<<16384, 256, 0, stream>>>(wo, woh, 4194304);

    gemm256<f16><<<384, 512, 0, stream>>>(xh, wqkvh, qkvh, 4096, 6144, 4096);

    rope_qk<<<40960, 256, 0, stream>>>(qkvh, freqs, qhp, kkp);
    transpose_v<<<dim3(32, 2, 16), 256, 0, stream>>>(qkvh, vvt);

    attn_fused<<<dim3(8, 32, 2), 512, 0, stream>>>(qhp, kkp, vvt, seql, attnh);

    gemm256<float><<<256, 512, 0, stream>>>(attnh, woh, out, 4096, 4096, 4096);
}